// Round 3
// baseline (409.589 us; speedup 1.0000x reference)
//
#include <hip/hip_runtime.h>

#define D 128
#define NBSHIFT 9           // 512 nodes per bucket -> ~196 buckets/blocks
#define NB (1 << NBSHIFT)
#define PEPB 8192           // edges per partition block (512 threads x 16)
#define BINS 256            // padded bucket-count for LDS hists/scans

typedef __attribute__((ext_vector_type(8))) short bf16x8;
typedef __attribute__((ext_vector_type(4))) float floatx4;

__device__ __forceinline__ float bflo(unsigned int u){ return __uint_as_float(u << 16); }
__device__ __forceinline__ float bfhi(unsigned int u){ return __uint_as_float(u & 0xffff0000u); }
__device__ __forceinline__ unsigned int f2bfbits(float f){
    unsigned int x = __float_as_uint(f);
    return (x + 0x7fffu + ((x >> 16) & 1u)) >> 16;  // RNE, finite inputs
}

// ---- bucket counts: LDS histogram, <=BINS global adds per block ----
__global__ __launch_bounds__(512) void k_bcount(const int* __restrict__ dst, int* __restrict__ bcnt, int E){
    __shared__ int hist[BINS];
    int t = threadIdx.x;
    int base = blockIdx.x * PEPB;
    if (t < BINS) hist[t] = 0;
    __syncthreads();
#pragma unroll
    for (int j = 0; j < 16; ++j){
        int e = base + j * 512 + t;
        if (e < E) atomicAdd(&hist[dst[e] >> NBSHIFT], 1);
    }
    __syncthreads();
    if (t < BINS && hist[t] > 0) atomicAdd(&bcnt[t], hist[t]);
}

// ---- parallel 1-block scan of bucket counts -> bases + cursors; rowStart[N]=E ----
__global__ __launch_bounds__(256) void k_bscan(const int* __restrict__ bcnt, int* __restrict__ bbase,
                                               int* __restrict__ bcur, int* __restrict__ rowStartN, int NBK){
    __shared__ int sc[256];
    int t = threadIdx.x;
    int v = (t < NBK) ? bcnt[t] : 0;
    sc[t] = v;
    __syncthreads();
    for (int off = 1; off < 256; off <<= 1){
        int u = (t >= off) ? sc[t - off] : 0;
        __syncthreads();
        sc[t] += u;
        __syncthreads();
    }
    if (t < NBK){
        int ex = sc[t] - v;
        bbase[t] = ex;
        bcur[t] = ex;
    }
    if (t == 255){
        bbase[NBK] = sc[255];     // = E
        *rowStartN = sc[255];
    }
}

// ---- pass 1: LDS-staged partition of edges into dst-buckets; packed uint32 ----
// pack = src | (dstLow << 20)   (src < 2^20, dstLow = 9 bits)
__global__ __launch_bounds__(512) void k_bucket(const int* __restrict__ src, const int* __restrict__ dst,
                                                int* __restrict__ bcur, unsigned int* __restrict__ edge1,
                                                int NBK, int E){
    __shared__ int hist[BINS], lstart[BINS], lcur[BINS], gbase[BINS];
    __shared__ unsigned int stage[PEPB];
    int t = threadIdx.x;
    int base = blockIdx.x * PEPB;
    int tot = min(PEPB, E - base);
    if (t < BINS) hist[t] = 0;
    __syncthreads();

    unsigned int ent[16]; int bk[16];
#pragma unroll
    for (int j = 0; j < 16; ++j){
        int e = base + j * 512 + t;
        bool ok = (e < E);
        int s = 0, d = 0;
        if (ok){
            s = src[e]; d = dst[e];
            atomicAdd(&hist[d >> NBSHIFT], 1);
        }
        ent[j] = (unsigned)s | (((unsigned)d & (NB - 1)) << 20);
        bk[j] = ok ? (d >> NBSHIFT) : -1;
    }
    __syncthreads();
    if (t < BINS) lstart[t] = hist[t];
    __syncthreads();
    for (int off = 1; off < BINS; off <<= 1){
        int v = 0;
        if (t < BINS && t >= off) v = lstart[t - off];
        __syncthreads();
        if (t < BINS) lstart[t] += v;
        __syncthreads();
    }
    if (t < BINS){
        int ex = lstart[t] - hist[t];
        lstart[t] = ex;
        lcur[t] = ex;
        if (t < NBK && hist[t] > 0) gbase[t] = atomicAdd(&bcur[t], hist[t]);
    }
    __syncthreads();
#pragma unroll
    for (int j = 0; j < 16; ++j){
        if (bk[j] >= 0){
            int pos = atomicAdd(&lcur[bk[j]], 1);
            stage[pos] = ent[j];
        }
    }
    __syncthreads();
    // write staged, bucket-grouped runs to globally reserved windows.
    // bucket of index i: largest b with lstart[b] <= i (binary search, 8 steps)
    for (int i = t; i < tot; i += 512){
        unsigned int e1 = stage[i];
        int lo = 0, hi = BINS - 1;
        while (lo < hi){
            int midb = (lo + hi + 1) >> 1;
            if (lstart[midb] <= i) lo = midb; else hi = midb - 1;
        }
        edge1[gbase[lo] + (i - lstart[lo])] = e1;
    }
}

// ---- pass 2: per-bucket degree hist + scan + CSR scatter (one block owns one
//      output window -> lines accumulate in one XCD's L2, no write amp) ----
__global__ __launch_bounds__(512) void k_csr2(const unsigned int* __restrict__ edge1,
                                              const int* __restrict__ bbase,
                                              int* __restrict__ rowStart, float* __restrict__ dinv,
                                              int* __restrict__ csr, int N){
    __shared__ int hist[NB];
    __shared__ int sc[NB];
    int b = blockIdx.x, t = threadIdx.x;
    int nbase = b << NBSHIFT;
    int nn = min(N - nbase, NB);
    int ebeg = bbase[b], eend = bbase[b + 1];

    hist[t] = 0;
    __syncthreads();
    for (int i = ebeg + t; i < eend; i += 512)
        atomicAdd(&hist[(edge1[i] >> 20) & (NB - 1)], 1);
    __syncthreads();
    sc[t] = hist[t];
    __syncthreads();
    for (int off = 1; off < NB; off <<= 1){
        int v = (t >= off) ? sc[t - off] : 0;
        __syncthreads();
        sc[t] += v;
        __syncthreads();
    }
    // sc inclusive; cursor/global offset = ebeg + (sc - hist)
    {
        int cur = ebeg + sc[t] - hist[t];
        sc[t] = cur;
        if (t < nn){
            rowStart[nbase + t] = cur;
            dinv[nbase + t] = rsqrtf((float)hist[t] + 1.0f);  // +1 self-loop
        }
    }
    __syncthreads();
    for (int i = ebeg + t; i < eend; i += 512){
        unsigned int p = edge1[i];
        int pos = atomicAdd(&sc[(p >> 20) & (NB - 1)], 1);
        csr[pos] = (int)(p & 0xFFFFFu);
    }
}

// ---- transpose + fp32->bf16 weights ----
__global__ __launch_bounds__(256) void k_wtrans(const float* __restrict__ W1,
                                                const float* __restrict__ W2,
                                                unsigned short* __restrict__ Wt1,
                                                unsigned short* __restrict__ Wt2){
    int i = blockIdx.x * 256 + threadIdx.x;
    const float* Ws; unsigned short* Wd; int j = i;
    if (i < 16384){ Ws = W1; Wd = Wt1; } else { Ws = W2; Wd = Wt2; j -= 16384; }
    int k = j >> 7, n = j & 127;
    Wd[n * 128 + k] = (unsigned short)f2bfbits(Ws[k * 128 + n]);
}

// ---- bf16 MFMA GEMM, templated on A dtype; H stored bf16 ----
template<bool A_BF16>
__global__ __launch_bounds__(256) void k_gemm(const void* __restrict__ Av,
                                              const unsigned short* __restrict__ Wt,
                                              unsigned short* __restrict__ Hout, int Nrows){
    int wave = threadIdx.x >> 6, lane = threadIdx.x & 63;
    int m = lane & 15, quad = lane >> 4;
    int row0 = blockIdx.x * 64 + wave * 16;
    int arow = row0 + m;
    int arowc = arow < Nrows ? arow : Nrows - 1;

    bf16x8 a[4];
    if (A_BF16){
        const unsigned short* Ap = (const unsigned short*)Av + (size_t)arowc * D + quad * 8;
#pragma unroll
        for (int kt = 0; kt < 4; ++kt) a[kt] = *(const bf16x8*)(Ap + kt * 32);
    } else {
        const float* Ap = (const float*)Av + (size_t)arowc * D + quad * 8;
#pragma unroll
        for (int kt = 0; kt < 4; ++kt){
            float4 v0 = *(const float4*)(Ap + kt * 32);
            float4 v1 = *(const float4*)(Ap + kt * 32 + 4);
            bf16x8 af;
            af[0] = (short)f2bfbits(v0.x); af[1] = (short)f2bfbits(v0.y);
            af[2] = (short)f2bfbits(v0.z); af[3] = (short)f2bfbits(v0.w);
            af[4] = (short)f2bfbits(v1.x); af[5] = (short)f2bfbits(v1.y);
            af[6] = (short)f2bfbits(v1.z); af[7] = (short)f2bfbits(v1.w);
            a[kt] = af;
        }
    }

    floatx4 acc[8];
#pragma unroll
    for (int nt = 0; nt < 8; ++nt) acc[nt] = (floatx4){0.f, 0.f, 0.f, 0.f};

    const unsigned short* Bp = Wt + m * D + quad * 8;
#pragma unroll
    for (int kt = 0; kt < 4; ++kt){
        bf16x8 bk[8];
#pragma unroll
        for (int nt = 0; nt < 8; ++nt) bk[nt] = *(const bf16x8*)(Bp + nt * 16 * D + kt * 32);
#pragma unroll
        for (int nt = 0; nt < 8; ++nt)
            acc[nt] = __builtin_amdgcn_mfma_f32_16x16x32_bf16(a[kt], bk[nt], acc[nt], 0, 0, 0);
    }
#pragma unroll
    for (int nt = 0; nt < 8; ++nt){
#pragma unroll
        for (int r = 0; r < 4; ++r){
            int rr = row0 + quad * 4 + r;
            if (rr < Nrows) Hout[(size_t)rr * D + nt * 16 + m] = (unsigned short)f2bfbits(acc[nt][r]);
        }
    }
}

// ---- fused gather-aggregate + bias + LayerNorm + ReLU ----
// wave = 1 node; lane li (0..15) owns channels 8*li..8*li+7 (uint4 = 16B);
// quarter q (0..3) processes a contiguous quarter of the CSR row.
// 3 dependency rounds per node: [rowStart/dinv] -> [csr x8 predicated] ->
// [h-rows x8 unconditional, inactive slots clamped to node 0 (L1-hot)].
template<bool OUT_BF16>
__global__ __launch_bounds__(256) void k_agg(const unsigned short* __restrict__ h,
                                             const int* __restrict__ rowStart,
                                             const int* __restrict__ csr,
                                             const float* __restrict__ dinv,
                                             const float* __restrict__ bias,
                                             const float* __restrict__ gamma,
                                             const float* __restrict__ beta,
                                             void* __restrict__ outv, int N){
    int node = blockIdx.x * 4 + (threadIdx.x >> 6);
    if (node >= N) return;
    int lane = threadIdx.x & 63;
    int q = lane >> 4, li = lane & 15;
    const uint4* hv4 = (const uint4*)h;

    int start = rowStart[node], end = rowStart[node + 1];
    float dv = dinv[node];

    float a0 = 0.f, a1 = 0.f, a2 = 0.f, a3 = 0.f, a4 = 0.f, a5 = 0.f, a6 = 0.f, a7 = 0.f;
    if (q == 0){
        uint4 hs = hv4[(size_t)node * 16 + li];
        float w = dv * dv;
        a0 = bflo(hs.x) * w; a1 = bfhi(hs.x) * w;
        a2 = bflo(hs.y) * w; a3 = bfhi(hs.y) * w;
        a4 = bflo(hs.z) * w; a5 = bfhi(hs.z) * w;
        a6 = bflo(hs.w) * w; a7 = bfhi(hs.w) * w;
    }

    int deg = end - start;
    int len = (deg + 3) >> 2;
    int cb = min(start + q * len, end);
    int ce = min(cb + len, end);
    int n = ce - cb;                      // active slots this quarter (<= len)

    // phase 1: csr indices, predicated, independent
    int s0 = 0, s1 = 0, s2 = 0, s3 = 0, s4 = 0, s5 = 0, s6 = 0, s7 = 0;
    if (n > 0) s0 = csr[cb + 0];
    if (n > 1) s1 = csr[cb + 1];
    if (n > 2) s2 = csr[cb + 2];
    if (n > 3) s3 = csr[cb + 3];
    if (n > 4) s4 = csr[cb + 4];
    if (n > 5) s5 = csr[cb + 5];
    if (n > 6) s6 = csr[cb + 6];
    if (n > 7) s7 = csr[cb + 7];

    // phase 2: h rows (unconditional; inactive -> node 0, L1-hot) + weights
    uint4 h0 = hv4[(size_t)s0 * 16 + li];
    uint4 h1 = hv4[(size_t)s1 * 16 + li];
    uint4 h2 = hv4[(size_t)s2 * 16 + li];
    uint4 h3 = hv4[(size_t)s3 * 16 + li];
    uint4 h4 = hv4[(size_t)s4 * 16 + li];
    uint4 h5 = hv4[(size_t)s5 * 16 + li];
    uint4 h6 = hv4[(size_t)s6 * 16 + li];
    uint4 h7 = hv4[(size_t)s7 * 16 + li];
    float w0 = (n > 0) ? dinv[s0] * dv : 0.f;
    float w1 = (n > 1) ? dinv[s1] * dv : 0.f;
    float w2 = (n > 2) ? dinv[s2] * dv : 0.f;
    float w3 = (n > 3) ? dinv[s3] * dv : 0.f;
    float w4 = (n > 4) ? dinv[s4] * dv : 0.f;
    float w5 = (n > 5) ? dinv[s5] * dv : 0.f;
    float w6 = (n > 6) ? dinv[s6] * dv : 0.f;
    float w7 = (n > 7) ? dinv[s7] * dv : 0.f;

    // phase 3: exec-masked unpack+fma (slots beyond max active skip via execz)
#define FMA8(HH, WW) \
    a0 = fmaf(bflo(HH.x), WW, a0); a1 = fmaf(bfhi(HH.x), WW, a1); \
    a2 = fmaf(bflo(HH.y), WW, a2); a3 = fmaf(bfhi(HH.y), WW, a3); \
    a4 = fmaf(bflo(HH.z), WW, a4); a5 = fmaf(bfhi(HH.z), WW, a5); \
    a6 = fmaf(bflo(HH.w), WW, a6); a7 = fmaf(bfhi(HH.w), WW, a7);
    if (n > 0){ FMA8(h0, w0) }
    if (n > 1){ FMA8(h1, w1) }
    if (n > 2){ FMA8(h2, w2) }
    if (n > 3){ FMA8(h3, w3) }
    if (n > 4){ FMA8(h4, w4) }
    if (n > 5){ FMA8(h5, w5) }
    if (n > 6){ FMA8(h6, w6) }
    if (n > 7){ FMA8(h7, w7) }

    // rare tail (deg > 32)
    for (int i = cb + 8; i < ce; ++i){
        int s = csr[i];
        float ws = dinv[s] * dv;
        uint4 hs = hv4[(size_t)s * 16 + li];
        FMA8(hs, ws)
    }
#undef FMA8

    // reduce partial sums across the 4 quarters
#define RED(A) A += __shfl_xor(A, 16, 64); A += __shfl_xor(A, 32, 64);
    RED(a0) RED(a1) RED(a2) RED(a3) RED(a4) RED(a5) RED(a6) RED(a7)
#undef RED

    // bias
    float4 bb0 = ((const float4*)bias)[li * 2];
    float4 bb1 = ((const float4*)bias)[li * 2 + 1];
    a0 += bb0.x; a1 += bb0.y; a2 += bb0.z; a3 += bb0.w;
    a4 += bb1.x; a5 += bb1.y; a6 += bb1.z; a7 += bb1.w;

    // LayerNorm stats across the 16 lanes of the quarter
    float s1v = a0 + a1 + a2 + a3 + a4 + a5 + a6 + a7;
    float s2v = a0*a0 + a1*a1 + a2*a2 + a3*a3 + a4*a4 + a5*a5 + a6*a6 + a7*a7;
#pragma unroll
    for (int off = 8; off > 0; off >>= 1){
        s1v += __shfl_xor(s1v, off, 64);
        s2v += __shfl_xor(s2v, off, 64);
    }
    float mu = s1v * (1.0f / 128.0f);
    float var = s2v * (1.0f / 128.0f) - mu * mu;
    float rstd = rsqrtf(var + 1e-5f);

    float4 gg0 = ((const float4*)gamma)[li * 2];
    float4 gg1 = ((const float4*)gamma)[li * 2 + 1];
    float4 be0 = ((const float4*)beta)[li * 2];
    float4 be1 = ((const float4*)beta)[li * 2 + 1];
    float o0 = fmaxf(fmaf((a0 - mu) * rstd, gg0.x, be0.x), 0.0f);
    float o1 = fmaxf(fmaf((a1 - mu) * rstd, gg0.y, be0.y), 0.0f);
    float o2 = fmaxf(fmaf((a2 - mu) * rstd, gg0.z, be0.z), 0.0f);
    float o3 = fmaxf(fmaf((a3 - mu) * rstd, gg0.w, be0.w), 0.0f);
    float o4 = fmaxf(fmaf((a4 - mu) * rstd, gg1.x, be1.x), 0.0f);
    float o5 = fmaxf(fmaf((a5 - mu) * rstd, gg1.y, be1.y), 0.0f);
    float o6 = fmaxf(fmaf((a6 - mu) * rstd, gg1.z, be1.z), 0.0f);
    float o7 = fmaxf(fmaf((a7 - mu) * rstd, gg1.w, be1.w), 0.0f);

    if (OUT_BF16){
        if (q == 0){
            uint4 o;
            o.x = f2bfbits(o0) | (f2bfbits(o1) << 16);
            o.y = f2bfbits(o2) | (f2bfbits(o3) << 16);
            o.z = f2bfbits(o4) | (f2bfbits(o5) << 16);
            o.w = f2bfbits(o6) | (f2bfbits(o7) << 16);
            ((uint4*)outv)[(size_t)node * 16 + li] = o;
        }
    } else {
        if (q == 0){
            floatx4 o = {o0, o1, o2, o3};
            __builtin_nontemporal_store(o, (floatx4*)outv + (size_t)node * 32 + li * 2);
        } else if (q == 1){
            floatx4 o = {o4, o5, o6, o7};
            __builtin_nontemporal_store(o, (floatx4*)outv + (size_t)node * 32 + li * 2 + 1);
        }
    }
}

extern "C" void kernel_launch(void* const* d_in, const int* in_sizes, int n_in,
                              void* d_out, int out_size, void* d_ws, size_t ws_size,
                              hipStream_t stream){
    const float* x   = (const float*)d_in[0];
    const int*   ei  = (const int*)d_in[1];
    const float* W1  = (const float*)d_in[2];
    const float* b1  = (const float*)d_in[3];
    const float* g1  = (const float*)d_in[4];
    const float* be1 = (const float*)d_in[5];
    const float* W2  = (const float*)d_in[6];
    const float* b2  = (const float*)d_in[7];
    const float* g2  = (const float*)d_in[8];
    const float* be2 = (const float*)d_in[9];
    float* out = (float*)d_out;

    const int N = in_sizes[0] / D;
    const int E = in_sizes[1] / 2;
    const int* src = ei;
    const int* dst = ei + E;

    char* w = (char*)d_ws;
    size_t off = 0;
    auto alloc = [&](size_t bytes) -> char* {
        char* p = w + off;
        off = (off + bytes + 255) & ~(size_t)255;
        return p;
    };
    const int NBK = (N + NB - 1) >> NBSHIFT;   // <= BINS assumed (N <= 128K)
    int*            bcnt     = (int*)alloc((size_t)BINS * 4);
    int*            bbase    = (int*)alloc((size_t)(NBK + 1) * 4);
    int*            bcur     = (int*)alloc((size_t)BINS * 4);
    int*            rowStart = (int*)alloc((size_t)(N + 1) * 4);
    float*          dinv     = (float*)alloc((size_t)N * 4);
    unsigned int*   edge1    = (unsigned int*)alloc((size_t)E * 4);
    int*            csr      = (int*)alloc((size_t)E * 4 + 64);   // +pad for ladder overshoot
    unsigned short* wt1      = (unsigned short*)alloc(16384 * 2);
    unsigned short* wt2      = (unsigned short*)alloc(16384 * 2);
    unsigned short* h        = (unsigned short*)alloc((size_t)N * D * 2);
    unsigned short* hmid     = (unsigned short*)d_out;  // bf16 mid activation in d_out

    (void)hipMemsetAsync(bcnt, 0, (size_t)BINS * 4, stream);

    int gP = (E + PEPB - 1) / PEPB;
    int gG = (N + 63) / 64;
    int gA = (N + 3) / 4;

    k_bcount<<<gP, 512, 0, stream>>>(dst, bcnt, E);
    k_bscan <<<1, 256, 0, stream>>>(bcnt, bbase, bcur, rowStart + N, NBK);
    k_bucket<<<gP, 512, 0, stream>>>(src, dst, bcur, edge1, NBK, E);
    k_csr2  <<<NBK, 512, 0, stream>>>(edge1, bbase, rowStart, dinv, csr, N);
    k_wtrans<<<128, 256, 0, stream>>>(W1, W2, wt1, wt2);

    // layer 1: gemm(x) -> h ; agg -> hmid (bf16, in d_out)
    k_gemm<false><<<gG, 256, 0, stream>>>(x, wt1, h, N);
    k_agg<true>  <<<gA, 256, 0, stream>>>(h, rowStart, csr, dinv, b1, g1, be1, hmid, N);
    // layer 2: gemm(hmid) -> h ; agg -> out (fp32, nontemporal)
    k_gemm<true> <<<gG, 256, 0, stream>>>(hmid, wt2, h, N);
    k_agg<false> <<<gA, 256, 0, stream>>>(h, rowStart, csr, dinv, b2, g2, be2, out, N);
}